// Round 1
// baseline (612.404 us; speedup 1.0000x reference)
//
#include <hip/hip_runtime.h>

using short8  = __attribute__((ext_vector_type(8))) short;
using ushort8 = __attribute__((ext_vector_type(8))) unsigned short;
using f32x4   = __attribute__((ext_vector_type(4))) float;

constexpr int   N = 8192;
constexpr int   D = 512;
constexpr float INV_T_LOG2E = 2.8853900817779268f;  // (1/0.5) * log2(e)
constexpr int   CSPLIT = 4;
constexpr int   COLS_PER_BLOCK = N / CSPLIT;        // 2048

static __device__ __forceinline__ unsigned short f2bf(float x) {
  unsigned u = __float_as_uint(x);
  unsigned r = (u + 0x7fffu + ((u >> 16) & 1u)) >> 16;   // RNE
  return (unsigned short)r;
}

// One wave per row; rows [0,N) -> out0, [N,2N) -> out1.
__global__ __launch_bounds__(256) void normalize_kernel(
    const float* __restrict__ in0, const float* __restrict__ in1,
    unsigned short* __restrict__ n0, unsigned short* __restrict__ n1) {
  int gw   = (blockIdx.x * 256 + threadIdx.x) >> 6;   // global wave id, [0, 2N)
  int lane = threadIdx.x & 63;
  const float* src = (gw < N) ? in0 + (size_t)gw * D : in1 + (size_t)(gw - N) * D;
  unsigned short* dst = (gw < N) ? n0 + (size_t)gw * D : n1 + (size_t)(gw - N) * D;

  const float4* s4 = reinterpret_cast<const float4*>(src) + (size_t)lane * 2;
  float4 v0 = s4[0], v1 = s4[1];
  float ss = v0.x*v0.x + v0.y*v0.y + v0.z*v0.z + v0.w*v0.w
           + v1.x*v1.x + v1.y*v1.y + v1.z*v1.z + v1.w*v1.w;
#pragma unroll
  for (int m = 1; m <= 32; m <<= 1) ss += __shfl_xor(ss, m);
  float scale = 1.0f / fmaxf(sqrtf(ss), 1e-12f);

  ushort8 o;
  o[0] = f2bf(v0.x * scale); o[1] = f2bf(v0.y * scale);
  o[2] = f2bf(v0.z * scale); o[3] = f2bf(v0.w * scale);
  o[4] = f2bf(v1.x * scale); o[5] = f2bf(v1.y * scale);
  o[6] = f2bf(v1.z * scale); o[7] = f2bf(v1.w * scale);
  *(reinterpret_cast<ushort8*>(dst) + lane) = o;
}

// Fused GEMM + exp + masked row-sum.
// Block: 4 waves, each wave owns 16 rows; block covers 64 rows x 2048 cols.
__global__ __launch_bounds__(256) void ntxent_main(
    const unsigned short* __restrict__ n0, const unsigned short* __restrict__ n1,
    const int* __restrict__ labels,
    float* __restrict__ part_pos, float* __restrict__ part_all) {
  int lane = threadIdx.x & 63;
  int wave = threadIdx.x >> 6;
  int lr   = lane & 15;           // col within 16-frag / row within A-frag
  int lhi  = lane >> 4;           // k-group / D-row group
  int rowbase  = blockIdx.x * 64 + wave * 16;
  int colstart = blockIdx.y * COLS_PER_BLOCK;

  // Preload this wave's A strip: 16 rows x 512 K into 64 VGPRs.
  // A-frag (16x16x32 bf16): lane l -> row=l&15, k = kk*32 + (l>>4)*8 + j
  short8 a[16];
  const short8* arow =
      reinterpret_cast<const short8*>(n0 + (size_t)(rowbase + lr) * D) + lhi;
#pragma unroll
  for (int kk = 0; kk < 16; ++kk) a[kk] = arow[kk * 4];

  // Row labels for the C/D layout: row = lhi*4 + r
  int labr[4];
#pragma unroll
  for (int r = 0; r < 4; ++r) labr[r] = labels[rowbase + lhi * 4 + r];

  float allacc[4] = {0.f, 0.f, 0.f, 0.f};
  float posacc[4] = {0.f, 0.f, 0.f, 0.f};

  for (int ct = 0; ct < COLS_PER_BLOCK / 64; ++ct) {
    int colbase = colstart + ct * 64;
    f32x4 acc[4];
    int labc[4];
    const short8* brow[4];
#pragma unroll
    for (int cf = 0; cf < 4; ++cf) {
      acc[cf] = (f32x4){0.f, 0.f, 0.f, 0.f};
      labc[cf] = labels[colbase + cf * 16 + lr];
      brow[cf] =
          reinterpret_cast<const short8*>(n1 + (size_t)(colbase + cf * 16 + lr) * D) + lhi;
    }
#pragma unroll
    for (int kk = 0; kk < 16; ++kk) {
#pragma unroll
      for (int cf = 0; cf < 4; ++cf) {
        short8 b = brow[cf][kk * 4];
        acc[cf] = __builtin_amdgcn_mfma_f32_16x16x32_bf16(a[kk], b, acc[cf], 0, 0, 0);
      }
    }
    // Epilogue: logits = dot/T; e = exp(logits) = exp2(dot * 2*log2e)
#pragma unroll
    for (int cf = 0; cf < 4; ++cf) {
#pragma unroll
      for (int r = 0; r < 4; ++r) {
        float e = exp2f(acc[cf][r] * INV_T_LOG2E);
        allacc[r] += e;
        if (labr[r] == labc[cf]) posacc[r] += e;
      }
    }
  }

  // Reduce across the 16 lanes sharing lhi (sum over cols)
#pragma unroll
  for (int m = 1; m <= 8; m <<= 1) {
#pragma unroll
    for (int r = 0; r < 4; ++r) {
      allacc[r] += __shfl_xor(allacc[r], m);
      posacc[r] += __shfl_xor(posacc[r], m);
    }
  }
  if (lr == 0) {
#pragma unroll
    for (int r = 0; r < 4; ++r) {
      int row = rowbase + lhi * 4 + r;
      part_all[blockIdx.y * N + row] = allacc[r];
      part_pos[blockIdx.y * N + row] = posacc[r];
    }
  }
}

__global__ __launch_bounds__(256) void final_reduce(
    const float* __restrict__ part_pos, const float* __restrict__ part_all,
    float* __restrict__ out) {
  __shared__ float red[256];
  float s = 0.f;
  for (int i = threadIdx.x; i < N; i += 256) {
    float a = 0.f, p = 0.f;
#pragma unroll
    for (int cs = 0; cs < CSPLIT; ++cs) {
      a += part_all[cs * N + i];
      p += part_pos[cs * N + i];
    }
    s += logf(a) - logf(p);
  }
  red[threadIdx.x] = s;
  __syncthreads();
  for (int off = 128; off > 0; off >>= 1) {
    if (threadIdx.x < off) red[threadIdx.x] += red[threadIdx.x + off];
    __syncthreads();
  }
  if (threadIdx.x == 0) out[0] = red[0] / (float)N;
}

extern "C" void kernel_launch(void* const* d_in, const int* in_sizes, int n_in,
                              void* d_out, int out_size, void* d_ws, size_t ws_size,
                              hipStream_t stream) {
  const float* out0   = (const float*)d_in[0];
  const float* out1   = (const float*)d_in[1];
  const int*   labels = (const int*)d_in[2];
  float*       out    = (float*)d_out;

  char* ws = (char*)d_ws;
  unsigned short* n0 = (unsigned short*)ws;                          // 8 MB
  unsigned short* n1 = (unsigned short*)(ws + (size_t)N * D * 2);    // 8 MB
  float* part_pos = (float*)(ws + (size_t)2 * N * D * 2);            // 128 KB
  float* part_all = part_pos + (size_t)CSPLIT * N;                   // 128 KB

  hipLaunchKernelGGL(normalize_kernel, dim3(2 * N / 4), dim3(256), 0, stream,
                     out0, out1, n0, n1);
  hipLaunchKernelGGL(ntxent_main, dim3(N / 64, CSPLIT), dim3(256), 0, stream,
                     n0, n1, labels, part_pos, part_all);
  hipLaunchKernelGGL(final_reduce, dim3(1), dim3(256), 0, stream,
                     part_pos, part_all, out);
}

// Round 3
// 173.977 us; speedup vs baseline: 3.5200x; 3.5200x over previous
//
#include <hip/hip_runtime.h>

using short8  = __attribute__((ext_vector_type(8))) short;
using ushort8 = __attribute__((ext_vector_type(8))) unsigned short;
using f32x4   = __attribute__((ext_vector_type(4))) float;

constexpr int   N = 8192;
constexpr int   D = 512;
constexpr float INV_T_LOG2E = 2.8853900817779268f;  // (1/0.5) * log2(e)
constexpr int   CGROUPS = 16;                        // col groups (partial sets)
constexpr int   CTILES_PER_GROUP = 4;                // 4 x 128 cols per group

static __device__ __forceinline__ unsigned short f2bf(float x) {
  unsigned u = __float_as_uint(x);
  unsigned r = (u + 0x7fffu + ((u >> 16) & 1u)) >> 16;   // RNE
  return (unsigned short)r;
}

static __device__ __forceinline__ void gld16(const unsigned short* g, unsigned short* l) {
  __builtin_amdgcn_global_load_lds(
      (const __attribute__((address_space(1))) void*)g,
      (__attribute__((address_space(3))) void*)l, 16, 0, 0);
}

// One wave per row; rows [0,N) -> out0, [N,2N) -> out1.
__global__ __launch_bounds__(256) void normalize_kernel(
    const float* __restrict__ in0, const float* __restrict__ in1,
    unsigned short* __restrict__ n0, unsigned short* __restrict__ n1) {
  int gw   = (blockIdx.x * 256 + threadIdx.x) >> 6;
  int lane = threadIdx.x & 63;
  const float* src = (gw < N) ? in0 + (size_t)gw * D : in1 + (size_t)(gw - N) * D;
  unsigned short* dst = (gw < N) ? n0 + (size_t)gw * D : n1 + (size_t)(gw - N) * D;

  const float4* s4 = reinterpret_cast<const float4*>(src) + (size_t)lane * 2;
  float4 v0 = s4[0], v1 = s4[1];
  float ss = v0.x*v0.x + v0.y*v0.y + v0.z*v0.z + v0.w*v0.w
           + v1.x*v1.x + v1.y*v1.y + v1.z*v1.z + v1.w*v1.w;
#pragma unroll
  for (int m = 1; m <= 32; m <<= 1) ss += __shfl_xor(ss, m);
  float scale = 1.0f / fmaxf(sqrtf(ss), 1e-12f);

  ushort8 o;
  o[0] = f2bf(v0.x * scale); o[1] = f2bf(v0.y * scale);
  o[2] = f2bf(v0.z * scale); o[3] = f2bf(v0.w * scale);
  o[4] = f2bf(v1.x * scale); o[5] = f2bf(v1.y * scale);
  o[6] = f2bf(v1.z * scale); o[7] = f2bf(v1.w * scale);
  *(reinterpret_cast<ushort8*>(dst) + lane) = o;
}

// Fused GEMM(bf16 MFMA) + exp + masked row-sums.
// Block = 256 thr = 4 waves; 128x128 output tile; BK=32; dbuf LDS; m97 structure.
__global__ __launch_bounds__(256) void ntxent_main(
    const unsigned short* __restrict__ n0, const unsigned short* __restrict__ n1,
    const int* __restrict__ labels,
    float* __restrict__ part_pos, float* __restrict__ part_all) {
  __shared__ unsigned short As[2][128 * 32];
  __shared__ unsigned short Bs[2][128 * 32];
  __shared__ float redA[2][64];
  __shared__ float redP[2][64];

  const int t    = threadIdx.x;
  const int lane = t & 63;
  const int wid  = t >> 6;
  const int lr   = lane & 15;
  const int lhi  = lane >> 4;
  const int wr   = wid >> 1;   // wave row quadrant (0/1)
  const int wc   = wid & 1;    // wave col quadrant (0/1)

  // Bijective XCD swizzle (gridDim.x = 1024, %8 == 0)
  const int nwg = gridDim.x;
  const int cpx = nwg >> 3;
  const int swz = (blockIdx.x & 7) * cpx + (blockIdx.x >> 3);
  const int rowtile = swz >> 4;        // 64 row tiles
  const int colgrp  = swz & 15;        // 16 col groups
  const int rowbase = rowtile * 128;

  // Staging source for A (row = rowbase + t/4 [+64], col = (t&3)*8 + kt*32)
  const unsigned short* gA0 = n0 + (size_t)(rowbase + (t >> 2)) * D + (t & 3) * 8;
  unsigned short* const lA = &As[0][0] + wid * 512;   // wave-uniform LDS base
  unsigned short* const lB = &Bs[0][0] + wid * 512;

  // Row labels for this wave's 64 rows: row = wr*64 + m*16 + lhi*4 + r
  int labr[4][4];
#pragma unroll
  for (int m = 0; m < 4; ++m)
#pragma unroll
    for (int r = 0; r < 4; ++r)
      labr[m][r] = labels[rowbase + wr * 64 + m * 16 + lhi * 4 + r];

  float allrow[4][4] = {};
  float posrow[4][4] = {};

  for (int ctile = 0; ctile < CTILES_PER_GROUP; ++ctile) {
    const int colbase = (colgrp * CTILES_PER_GROUP + ctile) * 128;
    const unsigned short* ga = gA0;
    const unsigned short* gb = n1 + (size_t)(colbase + (t >> 2)) * D + (t & 3) * 8;

    f32x4 acc[4][4];
#pragma unroll
    for (int m = 0; m < 4; ++m)
#pragma unroll
      for (int n = 0; n < 4; ++n) acc[m][n] = (f32x4){0.f, 0.f, 0.f, 0.f};

    // prologue: stage kt=0 into buf 0
    gld16(ga, lA);            gld16(ga + 64 * D, lA + 2048);
    gld16(gb, lB);            gld16(gb + 64 * D, lB + 2048);
    ga += 32; gb += 32;
    __syncthreads();

    int cur = 0;
    for (int kt = 0; kt < 16; ++kt) {
      if (kt < 15) {
        unsigned short* la = lA + (cur ^ 1) * (128 * 32);
        unsigned short* lb = lB + (cur ^ 1) * (128 * 32);
        gld16(ga, la);          gld16(ga + 64 * D, la + 2048);
        gld16(gb, lb);          gld16(gb + 64 * D, lb + 2048);
        ga += 32; gb += 32;
      }
      short8 a[4], b[4];
#pragma unroll
      for (int m = 0; m < 4; ++m)
        a[m] = *(const short8*)&As[cur][(wr * 64 + m * 16 + lr) * 32 + lhi * 8];
#pragma unroll
      for (int n = 0; n < 4; ++n)
        b[n] = *(const short8*)&Bs[cur][(wc * 64 + n * 16 + lr) * 32 + lhi * 8];
#pragma unroll
      for (int m = 0; m < 4; ++m)
#pragma unroll
        for (int n = 0; n < 4; ++n)
          acc[m][n] = __builtin_amdgcn_mfma_f32_16x16x32_bf16(a[m], b[n], acc[m][n], 0, 0, 0);
      __syncthreads();
      cur ^= 1;
    }

    // Epilogue: e = exp(dot/T) = exp2(dot * 2*log2e); masked accumulate.
    int labc[4];
#pragma unroll
    for (int n = 0; n < 4; ++n) labc[n] = labels[colbase + wc * 64 + n * 16 + lr];
#pragma unroll
    for (int m = 0; m < 4; ++m)
#pragma unroll
      for (int n = 0; n < 4; ++n)
#pragma unroll
        for (int r = 0; r < 4; ++r) {
          float e = exp2f(acc[m][n][r] * INV_T_LOG2E);
          allrow[m][r] += e;
          if (labr[m][r] == labc[n]) posrow[m][r] += e;
        }
  }

  // Reduce over the 16 lanes (lr) sharing lhi
#pragma unroll
  for (int msk = 1; msk <= 8; msk <<= 1)
#pragma unroll
    for (int m = 0; m < 4; ++m)
#pragma unroll
      for (int r = 0; r < 4; ++r) {
        allrow[m][r] += __shfl_xor(allrow[m][r], msk);
        posrow[m][r] += __shfl_xor(posrow[m][r], msk);
      }

  // Cross-wave reduce: wc=1 waves publish their half, wc=0 waves combine+store.
  if (wc == 1 && lr == 0) {
#pragma unroll
    for (int m = 0; m < 4; ++m)
#pragma unroll
      for (int r = 0; r < 4; ++r) {
        redA[wr][m * 16 + lhi * 4 + r] = allrow[m][r];
        redP[wr][m * 16 + lhi * 4 + r] = posrow[m][r];
      }
  }
  __syncthreads();
  if (wc == 0 && lr == 0) {
#pragma unroll
    for (int m = 0; m < 4; ++m)
#pragma unroll
      for (int r = 0; r < 4; ++r) {
        int idx = m * 16 + lhi * 4 + r;
        int row = rowbase + wr * 64 + idx;
        part_all[colgrp * N + row] = allrow[m][r] + redA[wr][idx];
        part_pos[colgrp * N + row] = posrow[m][r] + redP[wr][idx];
      }
  }
}

__global__ __launch_bounds__(256) void final_reduce(
    const float* __restrict__ part_pos, const float* __restrict__ part_all,
    float* __restrict__ out) {
  __shared__ float red[256];
  float s = 0.f;
  for (int i = threadIdx.x; i < N; i += 256) {
    float a = 0.f, p = 0.f;
#pragma unroll
    for (int cs = 0; cs < CGROUPS; ++cs) {
      a += part_all[cs * N + i];
      p += part_pos[cs * N + i];
    }
    s += logf(a) - logf(p);
  }
  red[threadIdx.x] = s;
  __syncthreads();
  for (int off = 128; off > 0; off >>= 1) {
    if (threadIdx.x < off) red[threadIdx.x] += red[threadIdx.x + off];
    __syncthreads();
  }
  if (threadIdx.x == 0) out[0] = red[0] / (float)N;
}

extern "C" void kernel_launch(void* const* d_in, const int* in_sizes, int n_in,
                              void* d_out, int out_size, void* d_ws, size_t ws_size,
                              hipStream_t stream) {
  const float* out0   = (const float*)d_in[0];
  const float* out1   = (const float*)d_in[1];
  const int*   labels = (const int*)d_in[2];
  float*       out    = (float*)d_out;

  char* ws = (char*)d_ws;
  unsigned short* n0 = (unsigned short*)ws;                          // 8 MB
  unsigned short* n1 = (unsigned short*)(ws + (size_t)N * D * 2);    // 8 MB
  float* part_pos = (float*)(ws + (size_t)2 * N * D * 2);            // 512 KB
  float* part_all = part_pos + (size_t)CGROUPS * N;                  // 512 KB

  hipLaunchKernelGGL(normalize_kernel, dim3(2 * N / 4), dim3(256), 0, stream,
                     out0, out1, n0, n1);
  hipLaunchKernelGGL(ntxent_main, dim3(64 * CGROUPS), dim3(256), 0, stream,
                     n0, n1, labels, part_pos, part_all);
  hipLaunchKernelGGL(final_reduce, dim3(1), dim3(256), 0, stream,
                     part_pos, part_all, out);
}